// Round 4
// baseline (864.883 us; speedup 1.0000x reference)
//
#include <hip/hip_runtime.h>
#include <math.h>

#define Bsz 512
#define Tsz 512
#define Fin 32
#define Hd 64
#define CHUNK 32
#define NCH (Tsz / CHUNK)

typedef float v2f __attribute__((ext_vector_type(2)));

// v_rcp_f32-based activations (no IEEE div sequence; ~1 ulp)
__device__ __forceinline__ float fsig(float x) {
    return __builtin_amdgcn_rcpf(1.0f + __expf(-x));
}
__device__ __forceinline__ float ftanh(float x) {
    return fmaf(2.0f, __builtin_amdgcn_rcpf(1.0f + __expf(-2.0f * x)), -1.0f);
}

// Pin float4 components into arch VGPRs (blocks AGPR parking; round-3 proven).
#define PIN4(v4) \
    asm volatile("" : "+v"((v4).x), "+v"((v4).y), "+v"((v4).z), "+v"((v4).w))

// ---------------- Layer 0: x[B,T,32] -> h1[B,T,64] ----------------
// R4 change: x rows are read straight from GLOBAL (wave-uniform address ->
// one 16B request/wave, L1-served) instead of LDS staging. This halves the
// LDS b128 broadcast traffic, which round-3 counters showed saturates the
// LDS pipe (8 waves x 32 reads x ~8cyc ~= the whole 1920-cyc step).
// Depth-1 pipeline: xv[] holds row t+1 (loads issued during step t-1);
// ax (x-dot) computed in the barrier shadow; row t+2 loads issued pre-barrier.
__global__ __launch_bounds__(256, 2)
void lstm_layer0(const float* __restrict__ x,
                 const float4* __restrict__ Wih4,
                 const float4* __restrict__ Whh4,
                 const float* __restrict__ bih,
                 const float* __restrict__ bhh,
                 float* __restrict__ h1out)
{
    __shared__ __align__(16) float hcopy[4][Hd]; // per-wave private h
    __shared__ float glds[2][Hd * 5];            // gates, stride 5

    const int tid  = threadIdx.x;
    const int lane = tid & 63;
    const int wv   = tid >> 6;
    const int wvu  = __builtin_amdgcn_readfirstlane(wv);
    const int b    = blockIdx.x;

    float4 wih[8];
#pragma unroll
    for (int q = 0; q < 8; ++q) wih[q] = Wih4[tid * 8 + q];
    float4 whh[16];
#pragma unroll
    for (int q = 0; q < 16; ++q) whh[q] = Whh4[tid * 16 + q];
    const float bias = bih[tid] + bhh[tid];

    float c = 0.0f;
    hcopy[wv][lane] = 0.0f;

    const float4* xsrc = (const float4*)(x + (size_t)b * Tsz * Fin); // 8 f4/row
    float* hout = h1out + (size_t)b * Tsz * Hd + lane;

    // prologue: row0 -> ax, prefetch row1
    float4 xv[8];
#pragma unroll
    for (int q = 0; q < 8; ++q) xv[q] = xsrc[q];
    float ax;
    {
        v2f a0 = {bias, 0.0f}, a1 = {0.0f, 0.0f};
#pragma unroll
        for (int q = 0; q < 8; ++q) {
            float4 t4 = xv[q];
            v2f b0 = {t4.x, t4.y}, b1 = {t4.z, t4.w};
            v2f w0 = {wih[q].x, wih[q].y}, w1 = {wih[q].z, wih[q].w};
            a0 = __builtin_elementwise_fma(b0, w0, a0);
            a1 = __builtin_elementwise_fma(b1, w1, a1);
        }
        ax = (a0.x + a0.y) + (a1.x + a1.y);
    }
#pragma unroll
    for (int q = 0; q < 8; ++q) xv[q] = xsrc[8 + q];
    __syncthreads();

    for (int ci = 0; ci < NCH; ++ci) {
#pragma unroll
        for (int q = 0; q < 8; ++q)  PIN4(wih[q]);
#pragma unroll
        for (int q = 0; q < 16; ++q) PIN4(whh[q]);
#pragma unroll 1
        for (int ct = 0; ct < CHUNK; ct += 2) {
#pragma unroll
            for (int pp = 0; pp < 2; ++pp) {   // glds parity compile-time
                const int t = ci * CHUNK + ct + pp;
                const float4* hrow = (const float4*)&hcopy[wv][0];

                v2f a0 = {ax, 0.0f}, a1 = {0.0f, 0.0f};
#pragma unroll
                for (int q = 0; q < 16; ++q) {
                    float4 hv = hrow[q];
                    v2f b0 = {hv.x, hv.y}, b1 = {hv.z, hv.w};
                    v2f w0 = {whh[q].x, whh[q].y}, w1 = {whh[q].z, whh[q].w};
                    a0 = __builtin_elementwise_fma(b0, w0, a0);
                    a1 = __builtin_elementwise_fma(b1, w1, a1);
                }
                float a = (a0.x + a0.y) + (a1.x + a1.y);
                if (wvu == 2) glds[pp][lane * 5 + wv] = ftanh(a);
                else          glds[pp][lane * 5 + wv] = fsig(a);

                // x-dot for t+1 from prefetched xv (loads issued last step)
                {
                    v2f a0x = {bias, 0.0f}, a1x = {0.0f, 0.0f};
#pragma unroll
                    for (int q = 0; q < 8; ++q) {
                        float4 t4 = xv[q];
                        v2f b0 = {t4.x, t4.y}, b1 = {t4.z, t4.w};
                        v2f w0 = {wih[q].x, wih[q].y}, w1 = {wih[q].z, wih[q].w};
                        a0x = __builtin_elementwise_fma(b0, w0, a0x);
                        a1x = __builtin_elementwise_fma(b1, w1, a1x);
                    }
                    ax = (a0x.x + a0x.y) + (a1x.x + a1x.y);
                }
                // issue loads for row t+2 (consumed next step)
                const int tn = (t + 2 < Tsz) ? (t + 2) : (Tsz - 1);
#pragma unroll
                for (int q = 0; q < 8; ++q) xv[q] = xsrc[(size_t)tn * 8 + q];

                __syncthreads();
                float gi = glds[pp][lane * 5 + 0];
                float gf = glds[pp][lane * 5 + 1];
                float gg = glds[pp][lane * 5 + 2];
                float go = glds[pp][lane * 5 + 3];
                c = fmaf(gf, c, gi * gg);
                float h = go * ftanh(c);
                hcopy[wv][lane] = h;
                if (wvu == 0) hout[(size_t)t * Hd] = h;
            }
        }
    }
}

// ------- Layer 1 + FC: h1[B,T,64] -> out[B] -------
__global__ __launch_bounds__(256, 2)
void lstm_layer1_fc(const float* __restrict__ h1,
                    const float4* __restrict__ Wih4,
                    const float4* __restrict__ Whh4,
                    const float* __restrict__ bih,
                    const float* __restrict__ bhh,
                    const float* __restrict__ fcW,
                    const float* __restrict__ fcb,
                    float* __restrict__ out)
{
    __shared__ __align__(16) float hcopy[4][Hd];
    __shared__ float glds[2][Hd * 5];

    const int tid  = threadIdx.x;
    const int lane = tid & 63;
    const int wv   = tid >> 6;
    const int wvu  = __builtin_amdgcn_readfirstlane(wv);
    const int b    = blockIdx.x;

    float4 wih[16];
#pragma unroll
    for (int q = 0; q < 16; ++q) wih[q] = Wih4[tid * 16 + q];
    float4 whh[16];
#pragma unroll
    for (int q = 0; q < 16; ++q) whh[q] = Whh4[tid * 16 + q];
    const float bias = bih[tid] + bhh[tid];

    float c  = 0.0f;
    float hl = 0.0f;
    hcopy[wv][lane] = 0.0f;

    const float4* xsrc = (const float4*)(h1 + (size_t)b * Tsz * Hd); // 16 f4/row

    float4 xv[16];
#pragma unroll
    for (int q = 0; q < 16; ++q) xv[q] = xsrc[q];
    float ax;
    {
        v2f a0 = {bias, 0.0f}, a1 = {0.0f, 0.0f};
#pragma unroll
        for (int q = 0; q < 16; ++q) {
            float4 t4 = xv[q];
            v2f b0 = {t4.x, t4.y}, b1 = {t4.z, t4.w};
            v2f w0 = {wih[q].x, wih[q].y}, w1 = {wih[q].z, wih[q].w};
            a0 = __builtin_elementwise_fma(b0, w0, a0);
            a1 = __builtin_elementwise_fma(b1, w1, a1);
        }
        ax = (a0.x + a0.y) + (a1.x + a1.y);
    }
#pragma unroll
    for (int q = 0; q < 16; ++q) xv[q] = xsrc[16 + q];
    __syncthreads();

    for (int ci = 0; ci < NCH; ++ci) {
#pragma unroll
        for (int q = 0; q < 16; ++q) PIN4(wih[q]);
#pragma unroll
        for (int q = 0; q < 16; ++q) PIN4(whh[q]);
#pragma unroll 1
        for (int ct = 0; ct < CHUNK; ct += 2) {
#pragma unroll
            for (int pp = 0; pp < 2; ++pp) {
                const int t = ci * CHUNK + ct + pp;
                const float4* hrow = (const float4*)&hcopy[wv][0];

                v2f a0 = {ax, 0.0f}, a1 = {0.0f, 0.0f};
#pragma unroll
                for (int q = 0; q < 16; ++q) {
                    float4 hv = hrow[q];
                    v2f b0 = {hv.x, hv.y}, b1 = {hv.z, hv.w};
                    v2f w0 = {whh[q].x, whh[q].y}, w1 = {whh[q].z, whh[q].w};
                    a0 = __builtin_elementwise_fma(b0, w0, a0);
                    a1 = __builtin_elementwise_fma(b1, w1, a1);
                }
                float a = (a0.x + a0.y) + (a1.x + a1.y);
                if (wvu == 2) glds[pp][lane * 5 + wv] = ftanh(a);
                else          glds[pp][lane * 5 + wv] = fsig(a);

                // x-dot for t+1 from prefetched xv
                {
                    v2f a0x = {bias, 0.0f}, a1x = {0.0f, 0.0f};
#pragma unroll
                    for (int q = 0; q < 16; ++q) {
                        float4 t4 = xv[q];
                        v2f b0 = {t4.x, t4.y}, b1 = {t4.z, t4.w};
                        v2f w0 = {wih[q].x, wih[q].y}, w1 = {wih[q].z, wih[q].w};
                        a0x = __builtin_elementwise_fma(b0, w0, a0x);
                        a1x = __builtin_elementwise_fma(b1, w1, a1x);
                    }
                    ax = (a0x.x + a0x.y) + (a1x.x + a1x.y);
                }
                // issue loads for row t+2
                const int tn = (t + 2 < Tsz) ? (t + 2) : (Tsz - 1);
#pragma unroll
                for (int q = 0; q < 16; ++q) xv[q] = xsrc[(size_t)tn * 16 + q];

                __syncthreads();
                float gi = glds[pp][lane * 5 + 0];
                float gf = glds[pp][lane * 5 + 1];
                float gg = glds[pp][lane * 5 + 2];
                float go = glds[pp][lane * 5 + 3];
                c  = fmaf(gf, c, gi * gg);
                hl = go * ftanh(c);
                hcopy[wv][lane] = hl;
            }
        }
    }
    // fused FC on last h2 (wave 0 only; hl is replicated across waves)
    if (wvu == 0) {
        float psum = hl * fcW[lane];
#pragma unroll
        for (int off = 32; off > 0; off >>= 1)
            psum += __shfl_down(psum, off);
        if (lane == 0) out[b] = psum + fcb[0];
    }
}

extern "C" void kernel_launch(void* const* d_in, const int* in_sizes, int n_in,
                              void* d_out, int out_size, void* d_ws, size_t ws_size,
                              hipStream_t stream)
{
    const float* x    = (const float*)d_in[0];
    const float* Wih0 = (const float*)d_in[1];
    const float* Whh0 = (const float*)d_in[2];
    const float* bih0 = (const float*)d_in[3];
    const float* bhh0 = (const float*)d_in[4];
    const float* Wih1 = (const float*)d_in[5];
    const float* Whh1 = (const float*)d_in[6];
    const float* bih1 = (const float*)d_in[7];
    const float* bhh1 = (const float*)d_in[8];
    const float* fcW  = (const float*)d_in[9];
    const float* fcb  = (const float*)d_in[10];
    float* out = (float*)d_out;
    float* h1  = (float*)d_ws; // B*T*H fp32 = 64 MB scratch

    lstm_layer0<<<dim3(Bsz), dim3(256), 0, stream>>>(
        x, (const float4*)Wih0, (const float4*)Whh0, bih0, bhh0, h1);
    lstm_layer1_fc<<<dim3(Bsz), dim3(256), 0, stream>>>(
        h1, (const float4*)Wih1, (const float4*)Whh1, bih1, bhh1, fcW, fcb, out);
}